// Round 1
// 7290.897 us; speedup vs baseline: 1.0332x; 1.0332x over previous
//
#include <hip/hip_runtime.h>
#include <math.h>

#define SQ 4096
#define HD 512
#define HHD 256
#define TS 8   // sequence rows per block in the parallel GEMMs

// LDS-only barrier: syncs the workgroup WITHOUT draining vmcnt.
#define BAR_LDS() asm volatile("s_waitcnt lgkmcnt(0)\n\ts_barrier" ::: "memory")
// wave-local LDS fence: drain own ds ops, forbid compiler reordering
#define FENCE_LDS() asm volatile("s_waitcnt lgkmcnt(0)" ::: "memory")
#define COMPILER_BARRIER() asm volatile("" ::: "memory")

typedef _Float16 h2 __attribute__((ext_vector_type(2)));

__device__ __forceinline__ h2 u2h(unsigned v) { union { unsigned u; h2 h; } x; x.u = v; return x.h; }
__device__ __forceinline__ unsigned h2u(h2 v) { union { unsigned u; h2 h; } x; x.h = v; return x.u; }

__device__ __forceinline__ float fdot2f(h2 a, h2 b, float c) {
#if __has_builtin(__builtin_amdgcn_fdot2)
  return __builtin_amdgcn_fdot2(a, b, c, false);
#else
  return fmaf((float)a.x, (float)b.x, fmaf((float)a.y, (float)b.y, c));
#endif
}

// ---------------- Kernel A: x = concat(inputs[0], note_emb[ids], chunk_emb[ids]) @ W_comb + b_comb
__global__ __launch_bounds__(512) void kA(const float* __restrict__ inputs,
                                          const int* __restrict__ nid,
                                          const int* __restrict__ cid,
                                          const float* __restrict__ note_emb,
                                          const float* __restrict__ chunk_emb,
                                          const float* __restrict__ Wc,
                                          const float* __restrict__ bc,
                                          float* __restrict__ xln) {
  __shared__ float xcat[TS][1536];
  const int t = threadIdx.x;          // 0..511
  const int s0 = blockIdx.x * TS;
  for (int si = 0; si < TS; ++si) {
    const int s = s0 + si;            // batch 0 only
    xcat[si][t]        = inputs[s * HD + t];
    xcat[si][512 + t]  = note_emb[nid[s] * HD + t];
    xcat[si][1024 + t] = chunk_emb[cid[s] * HD + t];
  }
  __syncthreads();
  float acc[TS];
  const float bcv = bc[t];
#pragma unroll
  for (int si = 0; si < TS; ++si) acc[si] = bcv;
  for (int r = 0; r < 1536; r += 4) {
    const float w0 = Wc[(r + 0) * HD + t];
    const float w1 = Wc[(r + 1) * HD + t];
    const float w2 = Wc[(r + 2) * HD + t];
    const float w3 = Wc[(r + 3) * HD + t];
#pragma unroll
    for (int si = 0; si < TS; ++si) {
      const float4 xv = *reinterpret_cast<const float4*>(&xcat[si][r]);
      acc[si] = fmaf(xv.x, w0, acc[si]);
      acc[si] = fmaf(xv.y, w1, acc[si]);
      acc[si] = fmaf(xv.z, w2, acc[si]);
      acc[si] = fmaf(xv.w, w3, acc[si]);
    }
  }
  for (int si = 0; si < TS; ++si) xln[(s0 + si) * HD + t] = acc[si];
}

// ---------------- Kernel B: in-place LayerNorm over H=512 per row
__global__ __launch_bounds__(256) void kB(float* __restrict__ xln,
                                          const float* __restrict__ g,
                                          const float* __restrict__ b) {
  __shared__ float red[4];
  __shared__ float mu_s, rs_s;
  const int s = blockIdx.x;
  const int t = threadIdx.x;          // 0..255
  const int wave = t >> 6, lane = t & 63;
  float v0 = xln[s * HD + t];
  float v1 = xln[s * HD + t + 256];
  float sum = v0 + v1;
#pragma unroll
  for (int o = 32; o >= 1; o >>= 1) sum += __shfl_down(sum, o, 64);
  if (lane == 0) red[wave] = sum;
  __syncthreads();
  if (t == 0) mu_s = (red[0] + red[1] + red[2] + red[3]) * (1.0f / 512.0f);
  __syncthreads();
  const float mu = mu_s;
  const float d0 = v0 - mu, d1 = v1 - mu;
  float vs = d0 * d0 + d1 * d1;
#pragma unroll
  for (int o = 32; o >= 1; o >>= 1) vs += __shfl_down(vs, o, 64);
  if (lane == 0) red[wave] = vs;
  __syncthreads();
  if (t == 0) rs_s = rsqrtf((red[0] + red[1] + red[2] + red[3]) * (1.0f / 512.0f) + 1e-12f);
  __syncthreads();
  const float rs = rs_s;
  xln[s * HD + t]       = d0 * rs * g[t] + b[t];
  xln[s * HD + t + 256] = d1 * rs * g[t + 256] + b[t + 256];
}

// ---------------- Kernel C: gx[dir][s][k*256+j] = x[s_eff] @ Wx[dir][k][:,j] + bg[dir][k][j]
__global__ __launch_bounds__(512) void kC(const float* __restrict__ xln,
                                          const float* __restrict__ Wx,
                                          const float* __restrict__ bg,
                                          float* __restrict__ gx) {
  __shared__ float xs[TS][HD];
  const int t = threadIdx.x;          // 0..511
  const int dir = blockIdx.y;
  const int s0 = blockIdx.x * TS;
  for (int si = 0; si < TS; ++si) {
    const int sx = dir ? (SQ - 1 - (s0 + si)) : (s0 + si);
    xs[si][t] = xln[sx * HD + t];
  }
  __syncthreads();
  const int k1 = t >> 8, j = t & 255;
  const int k2 = k1 + 2;
  const float* w1 = Wx + (size_t)(dir * 4 + k1) * HD * HHD + j;
  const float* w2 = Wx + (size_t)(dir * 4 + k2) * HD * HHD + j;
  float acc1[TS], acc2[TS];
  const float b1 = bg[(dir * 4 + k1) * HHD + j];
  const float b2 = bg[(dir * 4 + k2) * HHD + j];
#pragma unroll
  for (int si = 0; si < TS; ++si) { acc1[si] = b1; acc2[si] = b2; }
  for (int d = 0; d < HD; d += 4) {
    const float w1a = w1[(d + 0) * HHD], w1b = w1[(d + 1) * HHD];
    const float w1c = w1[(d + 2) * HHD], w1d = w1[(d + 3) * HHD];
    const float w2a = w2[(d + 0) * HHD], w2b = w2[(d + 1) * HHD];
    const float w2c = w2[(d + 2) * HHD], w2d = w2[(d + 3) * HHD];
#pragma unroll
    for (int si = 0; si < TS; ++si) {
      const float4 xv = *reinterpret_cast<const float4*>(&xs[si][d]);
      acc1[si] = fmaf(xv.x, w1a, acc1[si]);
      acc1[si] = fmaf(xv.y, w1b, acc1[si]);
      acc1[si] = fmaf(xv.z, w1c, acc1[si]);
      acc1[si] = fmaf(xv.w, w1d, acc1[si]);
      acc2[si] = fmaf(xv.x, w2a, acc2[si]);
      acc2[si] = fmaf(xv.y, w2b, acc2[si]);
      acc2[si] = fmaf(xv.z, w2c, acc2[si]);
      acc2[si] = fmaf(xv.w, w2d, acc2[si]);
    }
  }
  for (int si = 0; si < TS; ++si) {
    float* row = gx + ((size_t)(dir * SQ + s0 + si)) * 1024;
    row[t]       = acc1[si];
    row[t + 512] = acc2[si];
  }
}

__device__ __forceinline__ float tanh_fast(float x) {
  const float ax = fabsf(x);
  const float e  = __expf(-2.0f * ax);
  const float t  = __fdividef(1.0f - e, 1.0f + e);
  return copysignf(t, x);
}

// one pair (4*c4+q) of all 5 dot products
#define DOTQ(hu_, cu_, i_) { \
  const h2 hp_ = u2h(hu_); \
  a0 = fdot2f(wh[(i_)],      hp_, a0); \
  a1 = fdot2f(wh[32 + (i_)], hp_, a1); \
  a2 = fdot2f(wh[64 + (i_)], hp_, a2); \
  a3 = fdot2f(wh[96 + (i_)], hp_, a3); \
  ad = fdot2f(wd[(i_)], u2h(cu_), ad); }

// ---------------- Kernel R: sequential TLSTM recurrence — 2 WGs per direction.
// LATENCY-SPLIT rewrite (r7): previous version serialized the FULL 256-pair
// dot phase after the cross-CU exchange. Now K-slices are remapped so
// slices 0,1 = OWN 64 pairs (produced by the local epilogue — dependency is
// an LDS flag only) and slices 2,3 = PARTNER 64 pairs. Own-half waves (0-3)
// dot during the exchange window; partner-half waves (4-7) poll comm
// DIRECTLY (one tagged u64 per lane = their 32 h-pairs + 32 c-pairs),
// drop payloads in an LDS scratch and dot. The dedicated polling phase and
// the B2 barrier are gone; only B1 (partials -> epilogue) remains.
// pg/pd partials are parity double-buffered (partner waves legally run ahead
// of the local epilogue). Comm protocol (tag<<32 | f16-pair payload, parity
// double-buffer, relaxed agent atomics) is unchanged from the proven version.
// Dot-loop LDS reads vectorized: 16x ds_read_b128 instead of 64x ds_read_b32.
__global__ __launch_bounds__(512, 2) void kR(const float* __restrict__ gx,
                                             const float* __restrict__ Wh,
                                             const float* __restrict__ Wd,
                                             const float* __restrict__ bd,
                                             const float* __restrict__ times,
                                             unsigned long long* __restrict__ comm,
                                             float* __restrict__ hfin) {
  const int slot = blockIdx.x & 7;
  if (slot >= 2) return;
  const int dir = slot;
  const int wg  = blockIdx.x >> 3;    // 0..1 (blocks 0,1,8,9 active: partners share an XCD)
  const int t   = threadIdx.x;        // 0..511
  const int tt  = t & 127;            // col within the owned 128
  const int sk  = t >> 7;             // K-slice 0..3 (wave-pair uniform)
  const int skl = sk & 1;
  const bool own = (sk < 2);          // slices 0,1: own pairs; 2,3: partner pairs
  const int j   = wg * 128 + tt;      // owned global column
  const int lane = t & 63;

  // chunk layout: comm[((dir*2+w)*2 + parity)*128 + {p: h-pair, 64+p: c-pair}]
  unsigned long long* mybase = comm + (size_t)((dir * 2 + wg) * 2) * 128;
  const unsigned long long* pbase = comm + (size_t)((dir * 2 + (wg ^ 1)) * 2) * 128;

  // global h-pair base of this thread's K-slice (own half first, then partner's)
  const int basep = (wg ^ (sk >> 1)) * 64 + skl * 32;

  // ---- persistent packed-f16 weights (single-level unrolled; const indices) ----
  h2 wh[128];   // [gate k][pair p]: rows (2*(basep+p), +1), col j
#pragma unroll
  for (int i = 0; i < 128; ++i) {
    const int k = i >> 5, p = i & 31;
    const int row = 2 * (basep + p);
    const float w0 = Wh[((size_t)(dir * 4 + k) * HHD + row) * HHD + j];
    const float w1 = Wh[((size_t)(dir * 4 + k) * HHD + row + 1) * HHD + j];
    h2 v; v.x = (_Float16)w0; v.y = (_Float16)w1;
    wh[i] = v;
  }
  h2 wd[32];
#pragma unroll
  for (int i = 0; i < 32; ++i) {
    const int row = 2 * (basep + i);
    const float w0 = Wd[(size_t)dir * HHD * HHD + (size_t)row * HHD + j];
    const float w1 = Wd[(size_t)dir * HHD * HHD + (size_t)(row + 1) * HHD + j];
    h2 v; v.x = (_Float16)w0; v.y = (_Float16)w1;
    wd[i] = v;
  }

  __shared__ __align__(16) unsigned own_h[64];   // own 64 pairs, packed f16x2
  __shared__ __align__(16) unsigned own_c[64];
  __shared__ __align__(16) unsigned pscr[2][64]; // partner payload scratch [skl][0..31:h, 32..63:c]
  __shared__ float pg[2][4][4][128];             // [parity][gate][slice][col]
  __shared__ float pd[2][4][128];                // [parity][slice][col]
  __shared__ unsigned hflag[2];                  // epilogue progress (per producing wave)
  __shared__ float T_pre[SQ];

  for (int s = t; s < SQ; s += 512) {
    const int sidx = dir ? ((s == 0) ? 0 : (SQ - s)) : s;
    T_pre[s] = 1.0f / logf(times[sidx] + 2.7182818284590452354f);
  }
  if (t < 64) { own_h[t] = 0u; own_c[t] = 0u; }
  if (t == 0) { hflag[0] = 0u; hflag[1] = 0u; }
  __syncthreads();                     // prologue only

  const float bdv = (t < 128) ? bd[dir * HHD + j] : 0.0f;
  const float* gxd = gx + (size_t)dir * SQ * 1024 + j;   // +k*256 per gate
  float g0 = 0, g1 = 0, g2 = 0, g3 = 0;
  if (t < 128) { g0 = gxd[0]; g1 = gxd[256]; g2 = gxd[512]; g3 = gxd[768]; }

  float h_my = 0.0f, c_my = 0.0f;      // fp32 master state for own column (epilogue thr)

  // per-lane poll slot: lanes 0..31 -> partner h-pairs of this slice,
  // lanes 32..63 -> partner c-pairs of this slice
  const int pslot = (lane < 32) ? (skl * 32 + lane) : (64 + skl * 32 + (lane - 32));
  volatile unsigned* hf = hflag;

  for (int s = 0; s < SQ; ++s) {
    const int par = s & 1;
    // epilogue threads: prefetch next step's gx early (in flight during spin/dots)
    float n0 = 0, n1 = 0, n2 = 0, n3 = 0;
    if (t < 128 && s + 1 < SQ) {
      const float* row = gxd + (size_t)(s + 1) * 1024;
      n0 = row[0]; n1 = row[256]; n2 = row[512]; n3 = row[768];
    }

    const uint4* hp4;
    const uint4* cp4;
    if (own) {
      // wait for local epilogue(s-1): pure-LDS flag, never a cross-CU wait
      while (hf[0] != (unsigned)s || hf[1] != (unsigned)s) {}
      COMPILER_BARRIER();
      hp4 = (const uint4*)&own_h[skl * 32];
      cp4 = (const uint4*)&own_c[skl * 32];
    } else {
      // poll partner's tagged pairs directly, one u64 per lane
      unsigned pv = 0u;
      if (s > 0) {
        const unsigned long long* cptr = pbase + (size_t)((s + 1) & 1) * 128 + pslot;
        unsigned long long v;
        do {
          v = __hip_atomic_load(cptr, __ATOMIC_RELAXED, __HIP_MEMORY_SCOPE_AGENT);
        } while (__any((int)((unsigned)(v >> 32) != (unsigned)s)));
        pv = (unsigned)v;
      }
      pscr[skl][lane] = pv;            // both waves of a slice write identical values (benign)
      FENCE_LDS();
      hp4 = (const uint4*)&pscr[skl][0];
      cp4 = (const uint4*)&pscr[skl][32];
    }

    // ---- split-K dots: 32 pairs for col j, vectorized b128 LDS reads ----
    float a0 = 0, a1 = 0, a2 = 0, a3 = 0, ad = 0;
#pragma unroll
    for (int c4 = 0; c4 < 8; ++c4) {
      const uint4 H = hp4[c4];
      const uint4 C = cp4[c4];
      DOTQ(H.x, C.x, 4 * c4 + 0)
      DOTQ(H.y, C.y, 4 * c4 + 1)
      DOTQ(H.z, C.z, 4 * c4 + 2)
      DOTQ(H.w, C.w, 4 * c4 + 3)
    }
    pg[par][0][sk][tt] = a0;
    pg[par][1][sk][tt] = a1;
    pg[par][2][sk][tt] = a2;
    pg[par][3][sk][tt] = a3;
    pd[par][sk][tt]    = ad;
    BAR_LDS();                                         // B1: partials visible to epilogue

    if (t < 128) {
      // ---- epilogue: own col j ----
      const float s0 = pg[par][0][0][tt] + pg[par][0][1][tt] + pg[par][0][2][tt] + pg[par][0][3][tt];
      const float s1 = pg[par][1][0][tt] + pg[par][1][1][tt] + pg[par][1][2][tt] + pg[par][1][3][tt];
      const float s2 = pg[par][2][0][tt] + pg[par][2][1][tt] + pg[par][2][2][tt] + pg[par][2][3][tt];
      const float s3 = pg[par][3][0][tt] + pg[par][3][1][tt] + pg[par][3][2][tt] + pg[par][3][3][tt];
      const float sd = pd[par][0][tt] + pd[par][1][tt] + pd[par][2][tt] + pd[par][3][tt];
      const float iv  = __fdividef(1.0f, 1.0f + __expf(-(s0 + g0)));
      const float fv  = __fdividef(1.0f, 1.0f + __expf(-(s1 + g1)));
      const float ov  = __fdividef(1.0f, 1.0f + __expf(-(s2 + g2)));
      const float cgv = __fdividef(1.0f, 1.0f + __expf(-(s3 + g3)));
      const float c_st = tanh_fast(sd + bdv);
      const float T = T_pre[s];
      const float c_adj = c_my + (T - 1.0f) * c_st;
      const float ct = fv * c_adj + iv * cgv;
      const float hn = ov * tanh_fast(ct);
      c_my = ct;
      h_my = hn;
      // pack pairs via lane^1 shuffle (cols 2m,2m+1 are adjacent lanes)
      const float hn_o = __shfl(hn, lane ^ 1, 64);
      const float ct_o = __shfl(ct, lane ^ 1, 64);
      if ((lane & 1) == 0) {
        h2 hp_; hp_.x = (_Float16)hn; hp_.y = (_Float16)hn_o;
        h2 cp_; cp_.x = (_Float16)ct; cp_.y = (_Float16)ct_o;
        const unsigned hu = h2u(hp_), cu = h2u(cp_);
        const int pl = tt >> 1;                        // local pair 0..63
        // publish FIRST: it is on the partner's critical path
        unsigned long long* chunk = (unsigned long long*)mybase + (size_t)par * 128;
        const unsigned long long tg = ((unsigned long long)(unsigned)(s + 1)) << 32;
        __hip_atomic_store(chunk + pl,      tg | hu, __ATOMIC_RELAXED, __HIP_MEMORY_SCOPE_AGENT);
        __hip_atomic_store(chunk + 64 + pl, tg | cu, __ATOMIC_RELAXED, __HIP_MEMORY_SCOPE_AGENT);
        own_h[pl] = hu;
        own_c[pl] = cu;
      }
      FENCE_LDS();                                     // own_h/own_c drained before flag
      if (t == 0)  hf[0] = (unsigned)(s + 1);
      if (t == 64) hf[1] = (unsigned)(s + 1);
      g0 = n0; g1 = n1; g2 = n2; g3 = n3;
    }
  }
  if (t < 128) hfin[dir * HHD + j] = h_my;
}

// ---------------- Kernel D: logits = concat(hf,hb) @ W_cls + b_cls -> sigmoid -> out
__global__ __launch_bounds__(512) void kD(const float* __restrict__ hfin,
                                          const float* __restrict__ Wcls,
                                          const float* __restrict__ bcls,
                                          float* __restrict__ out) {
  __shared__ float red[8];
  const int t = threadIdx.x;          // 0..511
  float v = hfin[t] * Wcls[t];
#pragma unroll
  for (int o = 32; o >= 1; o >>= 1) v += __shfl_down(v, o, 64);
  if ((t & 63) == 0) red[t >> 6] = v;
  __syncthreads();
  if (t == 0) {
    float l = red[0] + red[1] + red[2] + red[3] + red[4] + red[5] + red[6] + red[7] + bcls[0];
    if (isnan(l) || isinf(l)) l = 0.0f;
    float p = 1.0f / (1.0f + expf(-l));
    if (isnan(p) || isinf(p)) p = 0.0f;
    out[0] = p;
  }
}

extern "C" void kernel_launch(void* const* d_in, const int* in_sizes, int n_in,
                              void* d_out, int out_size, void* d_ws, size_t ws_size,
                              hipStream_t stream) {
  const float* inputs    = (const float*)d_in[0];
  const float* times     = (const float*)d_in[1];
  const int*   nid       = (const int*)d_in[2];
  const int*   cid       = (const int*)d_in[3];
  const float* note_emb  = (const float*)d_in[4];
  const float* chunk_emb = (const float*)d_in[5];
  const float* W_comb    = (const float*)d_in[6];
  const float* b_comb    = (const float*)d_in[7];
  const float* ln_g      = (const float*)d_in[8];
  const float* ln_b      = (const float*)d_in[9];
  const float* Wx        = (const float*)d_in[10];
  const float* Wh        = (const float*)d_in[11];
  const float* bg        = (const float*)d_in[12];
  const float* Wd        = (const float*)d_in[13];
  const float* bd        = (const float*)d_in[14];
  const float* W_cls     = (const float*)d_in[15];
  const float* b_cls     = (const float*)d_in[16];

  float* ws   = (float*)d_ws;
  float* xln  = ws;                              // 4096*512    floats
  float* gx   = ws + (size_t)SQ * HD;            // 2*4096*1024 floats
  float* hfin = gx + (size_t)2 * SQ * 1024;      // 512 floats
  unsigned long long* comm = (unsigned long long*)(hfin + 512);  // 2*2*2*128 u64 = 8 KB

  kA<<<SQ / TS, 512, 0, stream>>>(inputs, nid, cid, note_emb, chunk_emb, W_comb, b_comb, xln);
  kB<<<SQ, 256, 0, stream>>>(xln, ln_g, ln_b);
  kC<<<dim3(SQ / TS, 2), 512, 0, stream>>>(xln, Wx, bg, gx);
  kR<<<10, 512, 0, stream>>>(gx, Wh, Wd, bd, times, comm, hfin);
  kD<<<1, 512, 0, stream>>>(hfin, W_cls, b_cls, (float*)d_out);
}